// Round 8
// baseline (91.952 us; speedup 1.0000x reference)
//
#include <hip/hip_runtime.h>
#include <hip/hip_bf16.h>

#define NB 4096
#define ND 512

typedef int i32x4 __attribute__((ext_vector_type(4)));
typedef int i32x8 __attribute__((ext_vector_type(8)));
typedef float f32x4 __attribute__((ext_vector_type(4)));

#define AS1 __attribute__((address_space(1)))
#define AS3 __attribute__((address_space(3)))

// ---- f32 -> fp8 e4m3fn (OCP), RNE, |x| <= 1 ----
__device__ __forceinline__ unsigned int f2e4m3(float x) {
    float a = fabsf(x);
    unsigned s = (__float_as_uint(x) >> 24) & 0x80u;
    if (a < 0.015625f) {                       // denorm/zero: step 2^-9
        int q = __float2int_rn(a * 512.0f);    // 0..8 (8 -> 0x08 == 2^-6)
        return s | (unsigned)q;
    }
    unsigned u = __float_as_uint(a);
    u += 0x7FFFFu + ((u >> 20) & 1u);          // RNE to 3-bit mantissa
    unsigned e8 = (u >> 23) - 120u;            // 1..7 for a in [2^-6, 1]
    unsigned m = (u >> 20) & 7u;
    return s | (e8 << 3) | m;
}

// ---------------- normalize + cast to fp8 (wave per row) + zero-init sums ----------------
__global__ __launch_bounds__(256) void nrm_kernel(
    const float* __restrict__ z0, const float* __restrict__ z1,
    const float* __restrict__ z2, unsigned char* __restrict__ nrm8,
    float* __restrict__ rowsum, float* __restrict__ colsum)
{
    const int w = threadIdx.x >> 6, lane = threadIdx.x & 63;
    const int row = blockIdx.x * 4 + w;
    const int p = blockIdx.y;
    if (lane == 0) {
        rowsum[p * NB + row] = 0.f;
        colsum[p * NB + row] = 0.f;
    }
    const float* z = (p == 0) ? z0 : (p == 1) ? z1 : z2;
    const float4* zr = (const float4*)(z + (size_t)row * ND);
    const float4 a = zr[lane * 2], b = zr[lane * 2 + 1];
    float ss = a.x * a.x + a.y * a.y + a.z * a.z + a.w * a.w
             + b.x * b.x + b.y * b.y + b.z * b.z + b.w * b.w;
    #pragma unroll
    for (int m = 32; m >= 1; m >>= 1) ss += __shfl_xor(ss, m);
    const float inv = 1.0f / fmaxf(sqrtf(ss), 1e-8f);
    uint2 o;
    o.x = f2e4m3(a.x * inv) | (f2e4m3(a.y * inv) << 8)
        | (f2e4m3(a.z * inv) << 16) | (f2e4m3(a.w * inv) << 24);
    o.y = f2e4m3(b.x * inv) | (f2e4m3(b.y * inv) << 8)
        | (f2e4m3(b.z * inv) << 16) | (f2e4m3(b.w * inv) << 24);
    *(uint2*)(nrm8 + ((size_t)p * NB + row) * ND + lane * 8) = o;
}

// ---------------- fused pair GEMM, MX-fp8: 128x128 tile, BK=128, 4 waves ----------------
// 64 KB LDS (A x2 + B x2 double-buffer) -> 2 independent blocks/CU; each
// block's gate/barrier bubbles hide under the other block. 4 K-tiles.
__global__ __launch_bounds__(256, 2) void pair_gemm_kernel(
    const unsigned char* __restrict__ nrm8,
    float* __restrict__ rowsum, float* __restrict__ colsum,
    float* __restrict__ diag)
{
    // XCD chunking: 3072 blocks; per pair each XCD owns 4 by x 32 bx
    // (A 256 KB + B 2 MB < 4 MB L2). Bijective.
    const int bid = blockIdx.x;
    const int xcd = bid & 7;
    const int rank = bid >> 3;           // 0..383
    const int p = rank >> 7;             // 0..2
    const int r = rank & 127;
    const int by = xcd * 4 + (r >> 5);   // 0..31
    const int bx = r & 31;               // 0..31
    const int ia = (p == 2) ? 1 : 0;
    const int ib = (p == 0) ? 1 : 2;

    const char* Ag = (const char*)nrm8 + ((size_t)ia * NB + (size_t)by * 128) * ND;
    const char* Bg = (const char*)nrm8 + ((size_t)ib * NB + (size_t)bx * 128) * ND;

    __shared__ char lds[65536];  // A: 2 x 16KB at 0; B: 2 x 16KB at 32768

    const int tid = threadIdx.x;
    const int lane = tid & 63;
    const int w = tid >> 6;
    const int wr = w >> 1, wc = w & 1;   // 2x2 wave grid; wave tile 64x64
    const int lr = lane & 15, lg = lane >> 4;

    // staging: op-tile = 128 rows x 128 B = 1024 chunks of 16B; 4 per thread.
    // row rr = c>>3; phys slot qp = c&7 holds logical qp^(rr&7) -> inverse-
    // swizzled SOURCE (rule 21), LDS dest linear (c*16). Src row stride = ND.
    int srcOff[4];
    #pragma unroll
    for (int q = 0; q < 4; ++q) {
        const int c = q * 256 + tid;
        const int rr = c >> 3;
        srcOff[q] = rr * ND + (((c & 7) ^ (rr & 7)) * 16);
    }

    // frag reads: lane-group lg covers logical slots {2lg, 2lg+1} (K bytes
    // [32lg, 32lg+32)); phys slot = logical ^ (lr&7). Uniform bank map:
    // 8 lanes per slot-quad -> 8 dword accesses/bank over the 8-cycle b128
    // transaction = conflict-free. Same map for A and B, so any HW-internal
    // k permutation inside the f8f6f4 operand cancels in A.B^T.
    const int s0 = ((2 * lg) ^ (lr & 7)) * 16;
    const int s1 = ((2 * lg + 1) ^ (lr & 7)) * 16;
    const int arow = (wr * 64 + lr) * 128;
    const int brow = (wc * 64 + lr) * 128;

    f32x4 acc[4][4] = {};

    #define STAGE(gsrc, dstbase) do {                                               \
        _Pragma("unroll")                                                           \
        for (int q = 0; q < 4; ++q)                                                 \
            __builtin_amdgcn_global_load_lds(                                       \
                (const AS1 void*)((gsrc) + srcOff[q]),                              \
                (AS3 void*)(lds + (dstbase) + q * 4096 + tid * 16), 16, 0, 0);      \
    } while (0)

    #define LDF(dst, base) do {                                                     \
        i32x4 lo_ = *(const i32x4*)((base) + s0);                                   \
        i32x4 hi_ = *(const i32x4*)((base) + s1);                                   \
        dst = __builtin_shufflevector(lo_, hi_, 0, 1, 2, 3, 4, 5, 6, 7);            \
    } while (0)

    #define SC 0x7F7F7F7F

    // prologue: tile 0 into read buffers, drain, sync
    STAGE(Ag, 0);
    STAGE(Bg, 32768);
    asm volatile("s_waitcnt vmcnt(0)" ::: "memory");
    __builtin_amdgcn_s_barrier();

    int abR = 0, abS = 16384, bbR = 32768, bbS = 49152;
    const char* AgS = Ag + 128;
    const char* BgS = Bg + 128;

    #pragma unroll 1
    for (int t = 0; t < 4; ++t) {
        // stage next tile into the spare buffers (issued before compute so the
        // L2 DMA latency hides under LDF+MFMA)
        if (t < 3) { STAGE(AgS, abS); STAGE(BgS, bbS); }

        const char* ab = lds + abR;
        const char* bb = lds + bbR;
        i32x8 af[4], bf[4];
        #pragma unroll
        for (int m = 0; m < 4; ++m) LDF(af[m], ab + arow + m * 2048);
        #pragma unroll
        for (int n = 0; n < 4; ++n) LDF(bf[n], bb + brow + n * 2048);

        __builtin_amdgcn_s_setprio(1);
        #pragma unroll
        for (int m = 0; m < 4; ++m)
            #pragma unroll
            for (int n = 0; n < 4; ++n)
                acc[m][n] = __builtin_amdgcn_mfma_scale_f32_16x16x128_f8f6f4(
                    af[m], bf[n], acc[m][n], 0, 0, 0, SC, 0, SC);
        __builtin_amdgcn_s_setprio(0);

        if (t < 3) {
            // gate: next tile's 8 DMA loads done; barrier also proves all waves
            // finished reading the buffers we stage into next iteration (their
            // MFMAs forced the lgkm waits before arrival).
            asm volatile("s_waitcnt vmcnt(0)" ::: "memory");
            __builtin_amdgcn_s_barrier();
            int tmp = abR; abR = abS; abS = tmp;
            tmp = bbR; bbR = bbS; bbS = tmp;
            AgS += 128; BgS += 128;
        }
    }
    #undef STAGE
    #undef LDF

    // ---- diag (pre-exp): C frag row = lg*4+j (within 16), col = lr ----
    if (bx == by && wr == wc) {
        #pragma unroll
        for (int m = 0; m < 4; ++m)
            #pragma unroll
            for (int j = 0; j < 4; ++j)
                if (lr == lg * 4 + j)
                    diag[p * NB + by * 128 + wr * 64 + m * 16 + lr] = acc[m][m][j];
    }

    // ---- epilogue: e = exp2(sim*10*log2e - 10*log2e), row/col partials ----
    constexpr float C10 = 14.42695040888963f;
    float rs[4][4];
    float cs[4] = {0.f, 0.f, 0.f, 0.f};
    #pragma unroll
    for (int m = 0; m < 4; ++m)
        #pragma unroll
        for (int j = 0; j < 4; ++j) rs[m][j] = 0.f;

    #pragma unroll
    for (int m = 0; m < 4; ++m)
        #pragma unroll
        for (int n = 0; n < 4; ++n)
            #pragma unroll
            for (int j = 0; j < 4; ++j) {
                float e = exp2f(fmaf(acc[m][n][j], C10, -C10));
                rs[m][j] += e;
                cs[n] += e;
            }

    #pragma unroll
    for (int m = 0; m < 4; ++m)
        #pragma unroll
        for (int j = 0; j < 4; ++j) {
            float v = rs[m][j];
            v += __shfl_xor(v, 1);
            v += __shfl_xor(v, 2);
            v += __shfl_xor(v, 4);
            v += __shfl_xor(v, 8);
            rs[m][j] = v;
        }
    #pragma unroll
    for (int n = 0; n < 4; ++n) {
        float v = cs[n];
        v += __shfl_xor(v, 16);
        v += __shfl_xor(v, 32);
        cs[n] = v;
    }

    float* rowp = rowsum + p * NB + by * 128 + wr * 64;
    float* colp = colsum + p * NB + bx * 128 + wc * 64;
    if (lr == 0) {
        #pragma unroll
        for (int m = 0; m < 4; ++m)
            #pragma unroll
            for (int j = 0; j < 4; ++j)
                atomicAdd(&rowp[m * 16 + lg * 4 + j], rs[m][j]);
    }
    if (lg == 0) {
        #pragma unroll
        for (int n = 0; n < 4; ++n)
            atomicAdd(&colp[n * 16 + lr], cs[n]);
    }
}

// ---------------- final reduce ----------------
__global__ __launch_bounds__(1024) void finalize_kernel(
    const float* __restrict__ rowsum, const float* __restrict__ colsum,
    const float* __restrict__ diag, float* __restrict__ out)
{
    float s = 0.f;
    for (int i = threadIdx.x; i < 3 * NB; i += 1024) {
        s += 0.5f * (logf(rowsum[i]) + logf(colsum[i])) + 10.0f - 10.0f * diag[i];
    }
    #pragma unroll
    for (int m = 32; m >= 1; m >>= 1) s += __shfl_xor(s, m);
    __shared__ float sw[16];
    if ((threadIdx.x & 63) == 0) sw[threadIdx.x >> 6] = s;
    __syncthreads();
    if (threadIdx.x == 0) {
        float t = 0.f;
        #pragma unroll
        for (int i = 0; i < 16; ++i) t += sw[i];
        out[0] = t * (1.0f / (3.0f * NB));
    }
}

extern "C" void kernel_launch(void* const* d_in, const int* in_sizes, int n_in,
                              void* d_out, int out_size, void* d_ws, size_t ws_size,
                              hipStream_t stream) {
    const float* z0 = (const float*)d_in[0];
    const float* z1 = (const float*)d_in[1];
    const float* z2 = (const float*)d_in[2];
    float* out = (float*)d_out;

    char* ws = (char*)d_ws;
    unsigned char* nrm8 = (unsigned char*)ws;               // 3*4096*512 fp8 = 6.3 MB
    const size_t nrm_bytes = (size_t)3 * NB * ND;
    float* rowsum = (float*)(ws + nrm_bytes);               // 3*4096 f32
    float* colsum = rowsum + 3 * NB;                        // 3*4096 f32
    float* diag = colsum + 3 * NB;                          // 3*4096 f32 (fully overwritten)

    nrm_kernel<<<dim3(NB / 4, 3), 256, 0, stream>>>(z0, z1, z2, nrm8, rowsum, colsum);
    pair_gemm_kernel<<<3072, 256, 0, stream>>>(nrm8, rowsum, colsum, diag);
    finalize_kernel<<<1, 1024, 0, stream>>>(rowsum, colsum, diag, out);
}

// Round 9
// 89.332 us; speedup vs baseline: 1.0293x; 1.0293x over previous
//
#include <hip/hip_runtime.h>
#include <hip/hip_bf16.h>

#define NB 4096
#define ND 512

typedef int i32x4 __attribute__((ext_vector_type(4)));
typedef int i32x8 __attribute__((ext_vector_type(8)));
typedef float f32x4 __attribute__((ext_vector_type(4)));

#define AS1 __attribute__((address_space(1)))
#define AS3 __attribute__((address_space(3)))

// ---- f32 -> fp8 e4m3fn (OCP), RNE, |x| <= 1 ----
__device__ __forceinline__ unsigned int f2e4m3(float x) {
    float a = fabsf(x);
    unsigned s = (__float_as_uint(x) >> 24) & 0x80u;
    if (a < 0.015625f) {                       // denorm/zero: step 2^-9
        int q = __float2int_rn(a * 512.0f);    // 0..8 (8 -> 0x08 == 2^-6)
        return s | (unsigned)q;
    }
    unsigned u = __float_as_uint(a);
    u += 0x7FFFFu + ((u >> 20) & 1u);          // RNE to 3-bit mantissa
    unsigned e8 = (u >> 23) - 120u;            // 1..7 for a in [2^-6, 1]
    unsigned m = (u >> 20) & 7u;
    return s | (e8 << 3) | m;
}

// ---------------- normalize + cast to fp8 (wave per row) + zero-init sums ----------------
__global__ __launch_bounds__(256) void nrm_kernel(
    const float* __restrict__ z0, const float* __restrict__ z1,
    const float* __restrict__ z2, unsigned char* __restrict__ nrm8,
    float* __restrict__ rowsum, float* __restrict__ colsum)
{
    const int w = threadIdx.x >> 6, lane = threadIdx.x & 63;
    const int row = blockIdx.x * 4 + w;
    const int p = blockIdx.y;
    if (lane == 0) {
        rowsum[p * NB + row] = 0.f;
        colsum[p * NB + row] = 0.f;
    }
    const float* z = (p == 0) ? z0 : (p == 1) ? z1 : z2;
    const float4* zr = (const float4*)(z + (size_t)row * ND);
    const float4 a = zr[lane * 2], b = zr[lane * 2 + 1];
    float ss = a.x * a.x + a.y * a.y + a.z * a.z + a.w * a.w
             + b.x * b.x + b.y * b.y + b.z * b.z + b.w * b.w;
    #pragma unroll
    for (int m = 32; m >= 1; m >>= 1) ss += __shfl_xor(ss, m);
    const float inv = 1.0f / fmaxf(sqrtf(ss), 1e-8f);
    uint2 o;
    o.x = f2e4m3(a.x * inv) | (f2e4m3(a.y * inv) << 8)
        | (f2e4m3(a.z * inv) << 16) | (f2e4m3(a.w * inv) << 24);
    o.y = f2e4m3(b.x * inv) | (f2e4m3(b.y * inv) << 8)
        | (f2e4m3(b.z * inv) << 16) | (f2e4m3(b.w * inv) << 24);
    *(uint2*)(nrm8 + ((size_t)p * NB + row) * ND + lane * 8) = o;
}

// ---------------- fused pair GEMM, MX-fp8: 128x128 tile, K staged in 2 halves ----------------
// LDS 64 KB (A[128][256] + B[128][256]) -> 2 independent blocks/CU. Each K-half
// (2 MFMA K-tiles) runs with ZERO barriers (pure LDF||MFMA dataflow); only 3
// sync points per block. Co-resident block covers the half-swap DMA.
__global__ __launch_bounds__(256, 2) void pair_gemm_kernel(
    const unsigned char* __restrict__ nrm8,
    float* __restrict__ rowsum, float* __restrict__ colsum,
    float* __restrict__ diag)
{
    // XCD chunking: 3072 blocks; per pair each XCD owns 4 by x 32 bx
    // (A 256 KB + B 2 MB < 4 MB L2). Bijective.
    const int bid = blockIdx.x;
    const int xcd = bid & 7;
    const int rank = bid >> 3;           // 0..383
    const int p = rank >> 7;             // 0..2
    const int r = rank & 127;
    const int by = xcd * 4 + (r >> 5);   // 0..31
    const int bx = r & 31;               // 0..31
    const int ia = (p == 2) ? 1 : 0;
    const int ib = (p == 0) ? 1 : 2;

    const char* Ag = (const char*)nrm8 + ((size_t)ia * NB + (size_t)by * 128) * ND;
    const char* Bg = (const char*)nrm8 + ((size_t)ib * NB + (size_t)bx * 128) * ND;

    __shared__ char lds[65536];  // A half at 0 (32 KB), B half at 32768

    const int tid = threadIdx.x;
    const int lane = tid & 63;
    const int w = tid >> 6;
    const int wr = w >> 1, wc = w & 1;   // 2x2 wave grid; wave tile 64x64
    const int lr = lane & 15, lg = lane >> 4;

    // ---- staging map: op-half = 128 rows x 256 B = 2048 chunks of 16B;
    // 8 chunks/thread/op. chunk c -> LDS linear c*16. Row rr = c>>4; phys slot
    // qp = c&15 holds logical ql = qp ^ (rr&15) -> inverse-swizzled SOURCE
    // (rule 21). Source row stride = ND; half h adds h*256.
    int srcOff[8];
    #pragma unroll
    for (int q = 0; q < 8; ++q) {
        const int c = q * 256 + tid;
        const int rr = c >> 4;
        srcOff[q] = rr * ND + (((c & 15) ^ (rr & 15)) * 16);
    }

    // ---- frag reads (16x16x128): lane (lr,lg), row R+lr, logical slots
    // {8kk+2lg, 8kk+2lg+1}; phys = logical ^ lr (rows 16-aligned). Byte:
    // slot^1 -> ^16, kk -> ^128. Uniform 8 accesses/bank-quad per ds_read_b128.
    const int s0 = ((2 * lg) ^ lr) * 16;
    int arow[4], brow[4];
    #pragma unroll
    for (int m = 0; m < 4; ++m) {
        arow[m] = (wr * 64 + m * 16 + lr) * 256;
        brow[m] = 32768 + (wc * 64 + m * 16 + lr) * 256;
    }

    f32x4 acc[4][4] = {};

    #define STAGEH(gsrc, dstbase, h) do {                                           \
        _Pragma("unroll")                                                           \
        for (int q = 0; q < 8; ++q)                                                 \
            __builtin_amdgcn_global_load_lds(                                       \
                (const AS1 void*)((gsrc) + srcOff[q] + (h) * 256),                  \
                (AS3 void*)(lds + (dstbase) + q * 4096 + tid * 16), 16, 0, 0);      \
    } while (0)

    #define LDF(dst, rowoff, kb) do {                                               \
        i32x4 lo_ = *(const i32x4*)(lds + (rowoff) + (s0 ^ (kb)));                  \
        i32x4 hi_ = *(const i32x4*)(lds + (rowoff) + (s0 ^ (kb) ^ 16));             \
        dst = __builtin_shufflevector(lo_, hi_, 0, 1, 2, 3, 4, 5, 6, 7);            \
    } while (0)

    #define SC 0x7F7F7F7F

    // one K-half = 2 MFMA K-tiles, zero barriers: LDF(kk=1) overlaps MFMA(kk=0)
    #define COMPUTE_HALF() do {                                                     \
        i32x8 af0[4], bf0[4], af1[4], bf1[4];                                       \
        _Pragma("unroll")                                                           \
        for (int m = 0; m < 4; ++m) LDF(af0[m], arow[m], 0);                        \
        _Pragma("unroll")                                                           \
        for (int n = 0; n < 4; ++n) LDF(bf0[n], brow[n], 0);                        \
        _Pragma("unroll")                                                           \
        for (int m = 0; m < 4; ++m) LDF(af1[m], arow[m], 128);                      \
        _Pragma("unroll")                                                           \
        for (int n = 0; n < 4; ++n) LDF(bf1[n], brow[n], 128);                      \
        __builtin_amdgcn_s_setprio(1);                                              \
        _Pragma("unroll")                                                           \
        for (int m = 0; m < 4; ++m)                                                 \
            _Pragma("unroll")                                                       \
            for (int n = 0; n < 4; ++n)                                             \
                acc[m][n] = __builtin_amdgcn_mfma_scale_f32_16x16x128_f8f6f4(       \
                    af0[m], bf0[n], acc[m][n], 0, 0, 0, SC, 0, SC);                 \
        _Pragma("unroll")                                                           \
        for (int m = 0; m < 4; ++m)                                                 \
            _Pragma("unroll")                                                       \
            for (int n = 0; n < 4; ++n)                                             \
                acc[m][n] = __builtin_amdgcn_mfma_scale_f32_16x16x128_f8f6f4(       \
                    af1[m], bf1[n], acc[m][n], 0, 0, 0, SC, 0, SC);                 \
        __builtin_amdgcn_s_setprio(0);                                              \
    } while (0)

    // prologue: stage half 0 (A+B), drain, sync
    STAGEH(Ag, 0, 0);
    STAGEH(Bg, 32768, 0);
    asm volatile("s_waitcnt vmcnt(0)" ::: "memory");
    __builtin_amdgcn_s_barrier();

    // half 0 compute (K bytes [0,256))
    COMPUTE_HALF();

    // half swap: all waves done READING (lgkm drained + barrier), then restage
    asm volatile("s_waitcnt lgkmcnt(0)" ::: "memory");
    __builtin_amdgcn_s_barrier();
    STAGEH(Ag, 0, 1);
    STAGEH(Bg, 32768, 1);
    asm volatile("s_waitcnt vmcnt(0)" ::: "memory");
    __builtin_amdgcn_s_barrier();

    // half 1 compute (K bytes [256,512))
    COMPUTE_HALF();

    #undef STAGEH
    #undef LDF
    #undef COMPUTE_HALF

    // ---- diag (pre-exp): C frag row = lg*4+j (within 16), col = lr ----
    if (bx == by && wr == wc) {
        #pragma unroll
        for (int m = 0; m < 4; ++m)
            #pragma unroll
            for (int j = 0; j < 4; ++j)
                if (lr == lg * 4 + j)
                    diag[p * NB + by * 128 + wr * 64 + m * 16 + lr] = acc[m][m][j];
    }

    // ---- epilogue: e = exp2(sim*10*log2e - 10*log2e), row/col partials ----
    constexpr float C10 = 14.42695040888963f;
    float rs[4][4];
    float cs[4] = {0.f, 0.f, 0.f, 0.f};
    #pragma unroll
    for (int m = 0; m < 4; ++m)
        #pragma unroll
        for (int j = 0; j < 4; ++j) rs[m][j] = 0.f;

    #pragma unroll
    for (int m = 0; m < 4; ++m)
        #pragma unroll
        for (int n = 0; n < 4; ++n)
            #pragma unroll
            for (int j = 0; j < 4; ++j) {
                float e = exp2f(fmaf(acc[m][n][j], C10, -C10));
                rs[m][j] += e;
                cs[n] += e;
            }

    #pragma unroll
    for (int m = 0; m < 4; ++m)
        #pragma unroll
        for (int j = 0; j < 4; ++j) {
            float v = rs[m][j];
            v += __shfl_xor(v, 1);
            v += __shfl_xor(v, 2);
            v += __shfl_xor(v, 4);
            v += __shfl_xor(v, 8);
            rs[m][j] = v;
        }
    #pragma unroll
    for (int n = 0; n < 4; ++n) {
        float v = cs[n];
        v += __shfl_xor(v, 16);
        v += __shfl_xor(v, 32);
        cs[n] = v;
    }

    float* rowp = rowsum + p * NB + by * 128 + wr * 64;
    float* colp = colsum + p * NB + bx * 128 + wc * 64;
    if (lr == 0) {
        #pragma unroll
        for (int m = 0; m < 4; ++m)
            #pragma unroll
            for (int j = 0; j < 4; ++j)
                atomicAdd(&rowp[m * 16 + lg * 4 + j], rs[m][j]);
    }
    if (lg == 0) {
        #pragma unroll
        for (int n = 0; n < 4; ++n)
            atomicAdd(&colp[n * 16 + lr], cs[n]);
    }
}

// ---------------- final reduce ----------------
__global__ __launch_bounds__(1024) void finalize_kernel(
    const float* __restrict__ rowsum, const float* __restrict__ colsum,
    const float* __restrict__ diag, float* __restrict__ out)
{
    float s = 0.f;
    for (int i = threadIdx.x; i < 3 * NB; i += 1024) {
        s += 0.5f * (logf(rowsum[i]) + logf(colsum[i])) + 10.0f - 10.0f * diag[i];
    }
    #pragma unroll
    for (int m = 32; m >= 1; m >>= 1) s += __shfl_xor(s, m);
    __shared__ float sw[16];
    if ((threadIdx.x & 63) == 0) sw[threadIdx.x >> 6] = s;
    __syncthreads();
    if (threadIdx.x == 0) {
        float t = 0.f;
        #pragma unroll
        for (int i = 0; i < 16; ++i) t += sw[i];
        out[0] = t * (1.0f / (3.0f * NB));
    }
}

extern "C" void kernel_launch(void* const* d_in, const int* in_sizes, int n_in,
                              void* d_out, int out_size, void* d_ws, size_t ws_size,
                              hipStream_t stream) {
    const float* z0 = (const float*)d_in[0];
    const float* z1 = (const float*)d_in[1];
    const float* z2 = (const float*)d_in[2];
    float* out = (float*)d_out;

    char* ws = (char*)d_ws;
    unsigned char* nrm8 = (unsigned char*)ws;               // 3*4096*512 fp8 = 6.3 MB
    const size_t nrm_bytes = (size_t)3 * NB * ND;
    float* rowsum = (float*)(ws + nrm_bytes);               // 3*4096 f32
    float* colsum = rowsum + 3 * NB;                        // 3*4096 f32
    float* diag = colsum + 3 * NB;                          // 3*4096 f32 (fully overwritten)

    nrm_kernel<<<dim3(NB / 4, 3), 256, 0, stream>>>(z0, z1, z2, nrm8, rowsum, colsum);
    pair_gemm_kernel<<<3072, 256, 0, stream>>>(nrm8, rowsum, colsum, diag);
    finalize_kernel<<<1, 1024, 0, stream>>>(rowsum, colsum, diag, out);
}